// Round 1
// baseline (586.107 us; speedup 1.0000x reference)
//
#include <hip/hip_runtime.h>

#define DH 128
#define NGRAPH 64

static __device__ __forceinline__ float4 f4fma(float a, float4 b, float4 c) {
  c.x = fmaf(a, b.x, c.x); c.y = fmaf(a, b.y, c.y);
  c.z = fmaf(a, b.z, c.z); c.w = fmaf(a, b.w, c.w);
  return c;
}

// ---------- degree / normalization ----------
__global__ void init_deg_k(int* __restrict__ deg, int n) {
  int i = blockIdx.x * blockDim.x + threadIdx.x;
  if (i < n) deg[i] = 1;  // self-loop
}

__global__ void count_deg_k(const int* __restrict__ col, int* __restrict__ deg, int e) {
  int i = blockIdx.x * blockDim.x + threadIdx.x;
  if (i < e) atomicAdd(&deg[col[i]], 1);
}

__global__ void dinv_k(const int* __restrict__ deg, float* __restrict__ dinv, int n) {
  int i = blockIdx.x * blockDim.x + threadIdx.x;
  if (i < n) dinv[i] = rsqrtf((float)deg[i]);
}

// ---------- exclusive scan of (deg-1) -> csr_ptr ----------
__global__ __launch_bounds__(512) void scan1_k(const int* __restrict__ deg, int* __restrict__ incl,
                                               int* __restrict__ blksum, int n) {
  __shared__ int s[512];
  int t = threadIdx.x;
  int i = blockIdx.x * 512 + t;
  int v = (i < n) ? (deg[i] - 1) : 0;
  s[t] = v;
  __syncthreads();
  #pragma unroll
  for (int off = 1; off < 512; off <<= 1) {
    int x = (t >= off) ? s[t - off] : 0;
    __syncthreads();
    s[t] += x;
    __syncthreads();
  }
  if (i < n) incl[i] = s[t];
  if (t == 511) blksum[blockIdx.x] = s[511];
}

__global__ __launch_bounds__(128) void scan2_k(int* __restrict__ blksum, int nb) {
  __shared__ int s[128];
  int t = threadIdx.x;
  int v = (t < nb) ? blksum[t] : 0;
  s[t] = v;
  __syncthreads();
  #pragma unroll
  for (int off = 1; off < 128; off <<= 1) {
    int x = (t >= off) ? s[t - off] : 0;
    __syncthreads();
    s[t] += x;
    __syncthreads();
  }
  if (t < nb) blksum[t] = s[t] - v;  // exclusive block offset
}

__global__ __launch_bounds__(512) void scan3_k(const int* __restrict__ deg, int* __restrict__ ptr,
                                               const int* __restrict__ blkoff, int* __restrict__ cursor,
                                               int n, int e) {
  int i = blockIdx.x * 512 + threadIdx.x;
  if (i < n) {
    int cnt = deg[i] - 1;
    int excl = ptr[i] - cnt + blkoff[i >> 9];
    ptr[i] = excl;
    cursor[i] = excl;
  }
  if (i == 0) ptr[n] = e;
}

__global__ void scatter_k(const int* __restrict__ row, const int* __restrict__ col,
                          int* __restrict__ cursor, int* __restrict__ csr_src, int e) {
  int i = blockIdx.x * blockDim.x + threadIdx.x;
  if (i < e) {
    int c = col[i];
    int pos = atomicAdd(&cursor[c], 1);
    csr_src[pos] = row[i];
  }
}

// ---------- f32 GEMM: C[M x 128] = A[M x 128] @ W[128 x 128] ----------
__global__ __launch_bounds__(256, 3) void gemm_k(const float* __restrict__ A, const float* __restrict__ W,
                                                 float* __restrict__ C, int M) {
  __shared__ float xs[64][64];    // 16 KB
  __shared__ float ws[64][128];   // 32 KB
  const int tid = threadIdx.x;
  const int tx = tid & 31;    // n0 = tx*4
  const int ty = tid >> 5;    // m0 = ty*8
  const int m_base = blockIdx.x * 64;

  float4 acc[8];
  #pragma unroll
  for (int i = 0; i < 8; i++) acc[i] = make_float4(0.f, 0.f, 0.f, 0.f);

  for (int kc = 0; kc < 128; kc += 64) {
    // stage W chunk (64x128)
    const float4* Wg = (const float4*)(W + kc * DH);
    float4* wsv = (float4*)ws;
    #pragma unroll
    for (int i = 0; i < 8; i++) wsv[tid + 256 * i] = Wg[tid + 256 * i];
    // stage A chunk (64 rows x 64 k)
    #pragma unroll
    for (int i = 0; i < 4; i++) {
      int f = tid + 256 * i;        // 0..1023
      int m = f >> 4;
      int k4 = (f & 15) << 2;
      int r = m_base + m;
      if (r >= M) r = M - 1;        // clamp (pad rows recompute row M-1)
      *(float4*)&xs[m][k4] = *(const float4*)(A + (size_t)r * DH + kc + k4);
    }
    __syncthreads();
    #pragma unroll 4
    for (int k = 0; k < 64; k += 4) {
      float4 wb0 = *(const float4*)&ws[k + 0][tx * 4];
      float4 wb1 = *(const float4*)&ws[k + 1][tx * 4];
      float4 wb2 = *(const float4*)&ws[k + 2][tx * 4];
      float4 wb3 = *(const float4*)&ws[k + 3][tx * 4];
      #pragma unroll
      for (int i = 0; i < 8; i++) {
        float4 xa = *(const float4*)&xs[ty * 8 + i][k];
        acc[i] = f4fma(xa.x, wb0, acc[i]);
        acc[i] = f4fma(xa.y, wb1, acc[i]);
        acc[i] = f4fma(xa.z, wb2, acc[i]);
        acc[i] = f4fma(xa.w, wb3, acc[i]);
      }
    }
    __syncthreads();
  }
  float* Cp = C + (size_t)(m_base + ty * 8) * DH + tx * 4;
  #pragma unroll
  for (int i = 0; i < 8; i++) *(float4*)(Cp + (size_t)i * DH) = acc[i];
}

// ---------- GCN aggregation: out[i] = relu( sum_{e->i} hW[src]*dinv[src]*dinv[i] + hW[i]*dinv[i]^2 + b ) ----------
__global__ __launch_bounds__(256) void aggregate_k(const float* __restrict__ hW, const float* __restrict__ dinv,
                                                   const int* __restrict__ ptr, const int* __restrict__ csr_src,
                                                   const float* __restrict__ bias, float* __restrict__ out, int n) {
  int wave = threadIdx.x >> 6;
  int lane = threadIdx.x & 63;
  int node = blockIdx.x * 4 + wave;
  if (node >= n) return;
  const float2* h2 = (const float2*)hW;
  float di = dinv[node];
  float2 acc = h2[(size_t)node * 64 + lane];
  acc.x *= di * di; acc.y *= di * di;
  int e0 = ptr[node], e1 = ptr[node + 1];
  for (int e = e0; e < e1; ++e) {
    int s = csr_src[e];
    float w = dinv[s] * di;
    float2 hv = h2[(size_t)s * 64 + lane];
    acc.x = fmaf(hv.x, w, acc.x);
    acc.y = fmaf(hv.y, w, acc.y);
  }
  float2 b = *(const float2*)(bias + lane * 2);
  acc.x = fmaxf(acc.x + b.x, 0.f);
  acc.y = fmaxf(acc.y + b.y, 0.f);
  ((float2*)out)[(size_t)node * 64 + lane] = acc;
}

// ---------- graph-size counting (sorted batch, wave-uniform fast path) ----------
__global__ void count_batch_k(const int* __restrict__ batch, int* __restrict__ gcnt, int n) {
  int i = blockIdx.x * blockDim.x + threadIdx.x;
  bool active = (i < n);
  int g = active ? batch[i] : 0;
  unsigned long long act = __ballot(active);
  if (!active) return;
  int first = __ffsll((long long)act) - 1;
  int g0 = __shfl(g, first);
  bool uni = __all(g == g0);
  int lane = threadIdx.x & 63;
  if (uni) {
    if (lane == first) atomicAdd(&gcnt[g], (int)__popcll(act));
  } else {
    atomicAdd(&gcnt[g], 1);
  }
}

// ---------- pooling partial sums (batch sorted; run-length flush) ----------
#define POOL_CHUNK 50
__global__ __launch_bounds__(128) void pool_partial_k(const float* __restrict__ h, const int* __restrict__ batch,
                                                      float* __restrict__ pooled, int n) {
  int n0 = blockIdx.x * POOL_CHUNK;
  if (n0 >= n) return;
  int n1 = n0 + POOL_CHUNK; if (n1 > n) n1 = n;
  int d = threadIdx.x;
  float acc = 0.f;
  int gp = batch[n0];
  for (int i = n0; i < n1; ++i) {
    int g = batch[i];
    if (g != gp) { atomicAdd(&pooled[(size_t)gp * DH + d], acc); acc = 0.f; gp = g; }
    acc += h[(size_t)i * DH + d];
  }
  atomicAdd(&pooled[(size_t)gp * DH + d], acc);
}

// ---------- final: out[g] = dot(pooled[g]/cnt[g], fcw) + fcb ----------
__global__ void final_k(const float* __restrict__ pooled, const int* __restrict__ gcnt,
                        const float* __restrict__ fcw, const float* __restrict__ fcb,
                        float* __restrict__ out) {
  int g = threadIdx.x;
  if (g >= NGRAPH) return;
  float c = fmaxf((float)gcnt[g], 1.f);
  float s = 0.f;
  #pragma unroll 4
  for (int d = 0; d < DH; ++d) s = fmaf(pooled[(size_t)g * DH + d] / c, fcw[d], s);
  out[g] = s + fcb[0];
}

extern "C" void kernel_launch(void* const* d_in, const int* in_sizes, int n_in,
                              void* d_out, int out_size, void* d_ws, size_t ws_size,
                              hipStream_t stream) {
  const float* x    = (const float*)d_in[0];
  const int*   ei   = (const int*)d_in[1];
  const int*   batch= (const int*)d_in[2];
  const float* W0   = (const float*)d_in[3];
  const float* b0   = (const float*)d_in[4];
  const float* W1   = (const float*)d_in[5];
  const float* b1   = (const float*)d_in[6];
  const float* W2   = (const float*)d_in[7];
  const float* b2   = (const float*)d_in[8];
  const float* fcw  = (const float*)d_in[9];
  const float* fcb  = (const float*)d_in[10];
  float* out = (float*)d_out;

  const int N = in_sizes[0] / DH;     // 50000
  const int E = in_sizes[1] / 2;      // 800000
  const int* row = ei;
  const int* col = ei + E;
  const int MPAD = ((N + 63) / 64) * 64;

  // workspace carve-up
  char* ws = (char*)d_ws;
  size_t off = 0;
  auto carve = [&](size_t bytes) -> char* {
    char* p = ws + off;
    off = (off + bytes + 255) & ~(size_t)255;
    return p;
  };
  float* bufA    = (float*)carve((size_t)MPAD * DH * 4);
  float* bufB    = (float*)carve((size_t)MPAD * DH * 4);
  int*   deg     = (int*)carve((size_t)N * 4);
  float* dinv    = (float*)carve((size_t)N * 4);
  int*   csr_ptr = (int*)carve((size_t)(N + 1) * 4);
  int*   cursor  = (int*)carve((size_t)N * 4);
  int*   csr_src = (int*)carve((size_t)E * 4);
  int*   blksum  = (int*)carve(128 * 4);
  int*   gcnt    = (int*)carve(NGRAPH * 4);
  float* pooled  = (float*)carve((size_t)NGRAPH * DH * 4);
  (void)ws_size; (void)n_in; (void)out_size;

  const int nb256N = (N + 255) / 256;
  const int nb256E = (E + 255) / 256;
  const int nbScan = (N + 511) / 512;

  hipMemsetAsync(gcnt, 0, NGRAPH * 4, stream);
  hipMemsetAsync(pooled, 0, (size_t)NGRAPH * DH * 4, stream);

  init_deg_k<<<nb256N, 256, 0, stream>>>(deg, N);
  count_deg_k<<<nb256E, 256, 0, stream>>>(col, deg, E);
  count_batch_k<<<nb256N, 256, 0, stream>>>(batch, gcnt, N);
  dinv_k<<<nb256N, 256, 0, stream>>>(deg, dinv, N);

  scan1_k<<<nbScan, 512, 0, stream>>>(deg, csr_ptr, blksum, N);
  scan2_k<<<1, 128, 0, stream>>>(blksum, nbScan);
  scan3_k<<<nbScan, 512, 0, stream>>>(deg, csr_ptr, blksum, cursor, N, E);
  scatter_k<<<nb256E, 256, 0, stream>>>(row, col, cursor, csr_src, E);

  const int gemmBlocks = MPAD / 64;
  const int aggBlocks = (N + 3) / 4;

  // layer 1: x -> bufA -> bufB
  gemm_k<<<gemmBlocks, 256, 0, stream>>>(x, W0, bufA, N);
  aggregate_k<<<aggBlocks, 256, 0, stream>>>(bufA, dinv, csr_ptr, csr_src, b0, bufB, N);
  // layer 2: bufB -> bufA -> bufB
  gemm_k<<<gemmBlocks, 256, 0, stream>>>(bufB, W1, bufA, N);
  aggregate_k<<<aggBlocks, 256, 0, stream>>>(bufA, dinv, csr_ptr, csr_src, b1, bufB, N);
  // layer 3
  gemm_k<<<gemmBlocks, 256, 0, stream>>>(bufB, W2, bufA, N);
  aggregate_k<<<aggBlocks, 256, 0, stream>>>(bufA, dinv, csr_ptr, csr_src, b2, bufB, N);

  const int poolBlocks = (N + POOL_CHUNK - 1) / POOL_CHUNK;
  pool_partial_k<<<poolBlocks, 128, 0, stream>>>(bufB, batch, pooled, N);
  final_k<<<1, 64, 0, stream>>>(pooled, gcnt, fcw, fcb, out);
}

// Round 2
// 502.819 us; speedup vs baseline: 1.1656x; 1.1656x over previous
//
#include <hip/hip_runtime.h>

#define DH 128
#define NGRAPH 64

static __device__ __forceinline__ float4 f4fma(float a, float4 b, float4 c) {
  c.x = fmaf(a, b.x, c.x); c.y = fmaf(a, b.y, c.y);
  c.z = fmaf(a, b.z, c.z); c.w = fmaf(a, b.w, c.w);
  return c;
}

// ---------- degree count (deg[] starts at 0 via memset; self-loop handled as +1 later) ----------
__global__ void count_deg_k(const int* __restrict__ col, int* __restrict__ deg, int e) {
  int i = blockIdx.x * blockDim.x + threadIdx.x;
  if (i < e) atomicAdd(&deg[col[i]], 1);
}

// ---------- exclusive scan of deg -> csr_ptr ----------
__global__ __launch_bounds__(512) void scan1_k(const int* __restrict__ deg, int* __restrict__ incl,
                                               int* __restrict__ blksum, int n) {
  __shared__ int s[512];
  int t = threadIdx.x;
  int i = blockIdx.x * 512 + t;
  int v = (i < n) ? deg[i] : 0;
  s[t] = v;
  __syncthreads();
  #pragma unroll
  for (int off = 1; off < 512; off <<= 1) {
    int x = (t >= off) ? s[t - off] : 0;
    __syncthreads();
    s[t] += x;
    __syncthreads();
  }
  if (i < n) incl[i] = s[t];
  if (t == 511) blksum[blockIdx.x] = s[511];
}

__global__ __launch_bounds__(128) void scan2_k(int* __restrict__ blksum, int nb) {
  __shared__ int s[128];
  int t = threadIdx.x;
  int v = (t < nb) ? blksum[t] : 0;
  s[t] = v;
  __syncthreads();
  #pragma unroll
  for (int off = 1; off < 128; off <<= 1) {
    int x = (t >= off) ? s[t - off] : 0;
    __syncthreads();
    s[t] += x;
    __syncthreads();
  }
  if (t < nb) blksum[t] = s[t] - v;  // exclusive block offset
}

// also computes dinv = rsqrt(deg+1)
__global__ __launch_bounds__(512) void scan3_k(const int* __restrict__ deg, int* __restrict__ ptr,
                                               const int* __restrict__ blkoff, int* __restrict__ cursor,
                                               float* __restrict__ dinv, int n, int e) {
  int i = blockIdx.x * 512 + threadIdx.x;
  if (i < n) {
    int cnt = deg[i];
    int excl = ptr[i] - cnt + blkoff[i >> 9];
    ptr[i] = excl;
    cursor[i] = excl;
    dinv[i] = rsqrtf((float)(cnt + 1));
  }
  if (i == 0) ptr[n] = e;
}

__global__ void scatter_k(const int* __restrict__ row, const int* __restrict__ col,
                          int* __restrict__ cursor, int* __restrict__ csr_src, int e) {
  int i = blockIdx.x * blockDim.x + threadIdx.x;
  if (i < e) {
    int c = col[i];
    int pos = atomicAdd(&cursor[c], 1);
    csr_src[pos] = row[i];
  }
}

// ---------- f32 GEMM with dinv-scaled epilogue: C[r] = (A@W)[r] * dinv[r] ----------
__global__ __launch_bounds__(256, 3) void gemm_k(const float* __restrict__ A, const float* __restrict__ W,
                                                 const float* __restrict__ dinv,
                                                 float* __restrict__ C, int M) {
  __shared__ float xs[64][64];    // 16 KB
  __shared__ float ws[64][128];   // 32 KB
  const int tid = threadIdx.x;
  const int tx = tid & 31;    // n0 = tx*4
  const int ty = tid >> 5;    // m0 = ty*8
  const int m_base = blockIdx.x * 64;

  float4 acc[8];
  #pragma unroll
  for (int i = 0; i < 8; i++) acc[i] = make_float4(0.f, 0.f, 0.f, 0.f);

  for (int kc = 0; kc < 128; kc += 64) {
    const float4* Wg = (const float4*)(W + kc * DH);
    float4* wsv = (float4*)ws;
    #pragma unroll
    for (int i = 0; i < 8; i++) wsv[tid + 256 * i] = Wg[tid + 256 * i];
    #pragma unroll
    for (int i = 0; i < 4; i++) {
      int f = tid + 256 * i;        // 0..1023
      int m = f >> 4;
      int k4 = (f & 15) << 2;
      int r = m_base + m;
      if (r >= M) r = M - 1;        // clamp (pad rows recompute row M-1)
      *(float4*)&xs[m][k4] = *(const float4*)(A + (size_t)r * DH + kc + k4);
    }
    __syncthreads();
    #pragma unroll 4
    for (int k = 0; k < 64; k += 4) {
      float4 wb0 = *(const float4*)&ws[k + 0][tx * 4];
      float4 wb1 = *(const float4*)&ws[k + 1][tx * 4];
      float4 wb2 = *(const float4*)&ws[k + 2][tx * 4];
      float4 wb3 = *(const float4*)&ws[k + 3][tx * 4];
      #pragma unroll
      for (int i = 0; i < 8; i++) {
        float4 xa = *(const float4*)&xs[ty * 8 + i][k];
        acc[i] = f4fma(xa.x, wb0, acc[i]);
        acc[i] = f4fma(xa.y, wb1, acc[i]);
        acc[i] = f4fma(xa.z, wb2, acc[i]);
        acc[i] = f4fma(xa.w, wb3, acc[i]);
      }
    }
    __syncthreads();
  }
  #pragma unroll
  for (int i = 0; i < 8; i++) {
    int r = m_base + ty * 8 + i;
    int rc = (r < M) ? r : (M - 1);
    float dsc = dinv[rc];
    acc[i].x *= dsc; acc[i].y *= dsc; acc[i].z *= dsc; acc[i].w *= dsc;
    *(float4*)(C + (size_t)r * DH + tx * 4) = acc[i];
  }
}

// ---------- GCN aggregation on pre-scaled h̃ = hW*dinv:
// out[i] = relu( dinv[i] * ( h̃[i] + sum_{e->i} h̃[src] ) + b )
__global__ __launch_bounds__(256) void aggregate_k(const float* __restrict__ hs, const float* __restrict__ dinv,
                                                   const int* __restrict__ ptr, const int* __restrict__ csr_src,
                                                   const float* __restrict__ bias, float* __restrict__ out, int n) {
  int wave = threadIdx.x >> 6;
  int lane = threadIdx.x & 63;
  int node = blockIdx.x * 4 + wave;
  if (node >= n) return;
  const float2* h2 = (const float2*)hs;
  float di = dinv[node];
  int e0 = ptr[node], e1 = ptr[node + 1];
  float2 a0 = h2[(size_t)node * 64 + lane];  // self term (already * dinv[node])
  float2 a1 = make_float2(0.f, 0.f);
  float2 a2 = make_float2(0.f, 0.f);
  float2 a3 = make_float2(0.f, 0.f);
  int e = e0;
  for (; e + 4 <= e1; e += 4) {
    int s0 = csr_src[e + 0];
    int s1 = csr_src[e + 1];
    int s2 = csr_src[e + 2];
    int s3 = csr_src[e + 3];
    float2 v0 = h2[(size_t)s0 * 64 + lane];
    float2 v1 = h2[(size_t)s1 * 64 + lane];
    float2 v2 = h2[(size_t)s2 * 64 + lane];
    float2 v3 = h2[(size_t)s3 * 64 + lane];
    a0.x += v0.x; a0.y += v0.y;
    a1.x += v1.x; a1.y += v1.y;
    a2.x += v2.x; a2.y += v2.y;
    a3.x += v3.x; a3.y += v3.y;
  }
  for (; e < e1; ++e) {
    int s = csr_src[e];
    float2 v = h2[(size_t)s * 64 + lane];
    a0.x += v.x; a0.y += v.y;
  }
  float sx = (a0.x + a1.x) + (a2.x + a3.x);
  float sy = (a0.y + a1.y) + (a2.y + a3.y);
  float2 b = *(const float2*)(bias + lane * 2);
  sx = fmaxf(fmaf(sx, di, b.x), 0.f);
  sy = fmaxf(fmaf(sy, di, b.y), 0.f);
  ((float2*)out)[(size_t)node * 64 + lane] = make_float2(sx, sy);
}

// ---------- graph-size counting (sorted batch, wave-uniform fast path) ----------
__global__ void count_batch_k(const int* __restrict__ batch, int* __restrict__ gcnt, int n) {
  int i = blockIdx.x * blockDim.x + threadIdx.x;
  bool active = (i < n);
  int g = active ? batch[i] : 0;
  unsigned long long act = __ballot(active);
  if (!active) return;
  int first = __ffsll((long long)act) - 1;
  int g0 = __shfl(g, first);
  bool uni = __all(g == g0);
  int lane = threadIdx.x & 63;
  if (uni) {
    if (lane == first) atomicAdd(&gcnt[g], (int)__popcll(act));
  } else {
    atomicAdd(&gcnt[g], 1);
  }
}

// ---------- pooling partial sums (batch sorted; run-length flush) ----------
#define POOL_CHUNK 50
__global__ __launch_bounds__(128) void pool_partial_k(const float* __restrict__ h, const int* __restrict__ batch,
                                                      float* __restrict__ pooled, int n) {
  int n0 = blockIdx.x * POOL_CHUNK;
  if (n0 >= n) return;
  int n1 = n0 + POOL_CHUNK; if (n1 > n) n1 = n;
  int d = threadIdx.x;
  float acc = 0.f;
  int gp = batch[n0];
  for (int i = n0; i < n1; ++i) {
    int g = batch[i];
    if (g != gp) { atomicAdd(&pooled[(size_t)gp * DH + d], acc); acc = 0.f; gp = g; }
    acc += h[(size_t)i * DH + d];
  }
  atomicAdd(&pooled[(size_t)gp * DH + d], acc);
}

// ---------- final: out[g] = dot(pooled[g]/cnt[g], fcw) + fcb ----------
__global__ void final_k(const float* __restrict__ pooled, const int* __restrict__ gcnt,
                        const float* __restrict__ fcw, const float* __restrict__ fcb,
                        float* __restrict__ out) {
  int g = threadIdx.x;
  if (g >= NGRAPH) return;
  float c = fmaxf((float)gcnt[g], 1.f);
  float s = 0.f;
  #pragma unroll 4
  for (int d = 0; d < DH; ++d) s = fmaf(pooled[(size_t)g * DH + d] / c, fcw[d], s);
  out[g] = s + fcb[0];
}

extern "C" void kernel_launch(void* const* d_in, const int* in_sizes, int n_in,
                              void* d_out, int out_size, void* d_ws, size_t ws_size,
                              hipStream_t stream) {
  const float* x    = (const float*)d_in[0];
  const int*   ei   = (const int*)d_in[1];
  const int*   batch= (const int*)d_in[2];
  const float* W0   = (const float*)d_in[3];
  const float* b0   = (const float*)d_in[4];
  const float* W1   = (const float*)d_in[5];
  const float* b1   = (const float*)d_in[6];
  const float* W2   = (const float*)d_in[7];
  const float* b2   = (const float*)d_in[8];
  const float* fcw  = (const float*)d_in[9];
  const float* fcb  = (const float*)d_in[10];
  float* out = (float*)d_out;

  const int N = in_sizes[0] / DH;     // 50000
  const int E = in_sizes[1] / 2;      // 800000
  const int* row = ei;
  const int* col = ei + E;
  const int MPAD = ((N + 63) / 64) * 64;

  // workspace carve-up
  char* ws = (char*)d_ws;
  size_t off = 0;
  auto carve = [&](size_t bytes) -> char* {
    char* p = ws + off;
    off = (off + bytes + 255) & ~(size_t)255;
    return p;
  };
  float* bufA    = (float*)carve((size_t)MPAD * DH * 4);
  float* bufB    = (float*)carve((size_t)MPAD * DH * 4);
  int*   deg     = (int*)carve((size_t)N * 4);
  float* dinv    = (float*)carve((size_t)N * 4);
  int*   csr_ptr = (int*)carve((size_t)(N + 1) * 4);
  int*   cursor  = (int*)carve((size_t)N * 4);
  int*   csr_src = (int*)carve((size_t)E * 4);
  int*   blksum  = (int*)carve(128 * 4);
  int*   gcnt    = (int*)carve(NGRAPH * 4);
  float* pooled  = (float*)carve((size_t)NGRAPH * DH * 4);
  (void)ws_size; (void)n_in; (void)out_size;

  const int nb256N = (N + 255) / 256;
  const int nb256E = (E + 255) / 256;
  const int nbScan = (N + 511) / 512;

  hipMemsetAsync(deg, 0, (size_t)N * 4, stream);
  hipMemsetAsync(gcnt, 0, NGRAPH * 4, stream);
  hipMemsetAsync(pooled, 0, (size_t)NGRAPH * DH * 4, stream);

  count_deg_k<<<nb256E, 256, 0, stream>>>(col, deg, E);
  count_batch_k<<<nb256N, 256, 0, stream>>>(batch, gcnt, N);

  scan1_k<<<nbScan, 512, 0, stream>>>(deg, csr_ptr, blksum, N);
  scan2_k<<<1, 128, 0, stream>>>(blksum, nbScan);
  scan3_k<<<nbScan, 512, 0, stream>>>(deg, csr_ptr, blksum, cursor, dinv, N, E);
  scatter_k<<<nb256E, 256, 0, stream>>>(row, col, cursor, csr_src, E);

  const int gemmBlocks = MPAD / 64;
  const int aggBlocks = (N + 3) / 4;

  // layer 1: x -> bufA (scaled) -> bufB
  gemm_k<<<gemmBlocks, 256, 0, stream>>>(x, W0, dinv, bufA, N);
  aggregate_k<<<aggBlocks, 256, 0, stream>>>(bufA, dinv, csr_ptr, csr_src, b0, bufB, N);
  // layer 2
  gemm_k<<<gemmBlocks, 256, 0, stream>>>(bufB, W1, dinv, bufA, N);
  aggregate_k<<<aggBlocks, 256, 0, stream>>>(bufA, dinv, csr_ptr, csr_src, b1, bufB, N);
  // layer 3
  gemm_k<<<gemmBlocks, 256, 0, stream>>>(bufB, W2, dinv, bufA, N);
  aggregate_k<<<aggBlocks, 256, 0, stream>>>(bufA, dinv, csr_ptr, csr_src, b2, bufB, N);

  const int poolBlocks = (N + POOL_CHUNK - 1) / POOL_CHUNK;
  pool_partial_k<<<poolBlocks, 128, 0, stream>>>(bufB, batch, pooled, N);
  final_k<<<1, 64, 0, stream>>>(pooled, gcnt, fcw, fcb, out);
}